// Round 1
// baseline (467.048 us; speedup 1.0000x reference)
//
#include <hip/hip_runtime.h>
#include <math.h>

// Problem constants (from reference): B=64, S=8192, D=64, fp32.
#define BB 64
#define SS 8192
#define DD 64

// Phase-1 S-chunks per batch (512 blocks => 2 blocks/CU for overlap)
constexpr int C1 = 8;
constexpr int CHUNK1 = SS / C1;   // 1024
// Phase-2 S-chunks per batch (1024 blocks => 4 blocks/CU)
constexpr int C2 = 16;
constexpr int CHUNK2 = SS / C2;   // 512

__device__ __forceinline__ float fmap(float x) {
    // elu(x) + 1 == (x > 0 ? x + 1 : exp(x))
    return x > 0.0f ? x + 1.0f : __expf(x);
}

// -------------------------------------------------------------------------
// Phase 1: kv[b][d][e] = sum_s fmap(k[b][s][d]) * v[b][s][e]
//          ksum[b][d]  = sum_s fmap(k[b][s][d])
// grid (C1, B), block 256. Partial sums combined with global fp32 atomics.
// -------------------------------------------------------------------------
__global__ __launch_bounds__(256) void phase1_kernel(
    const float* __restrict__ k,
    const float* __restrict__ v,
    float* __restrict__ kv_ws,    // [B][D][D], pre-zeroed
    float* __restrict__ ksum_ws)  // [B][D],   pre-zeroed
{
    __shared__ float Ks[64 * 64];
    __shared__ float Vs[64 * 64];

    const int t = threadIdx.x;
    const int b = blockIdx.y;
    const int s_chunk0 = blockIdx.x * CHUNK1;
    const int dgrp = t >> 4;       // 0..15
    const int egrp = t & 15;       // 0..15
    const int d0 = dgrp * 4;
    const int e0 = egrp * 4;

    const float* kb = k + (size_t)b * SS * DD;
    const float* vb = v + (size_t)b * SS * DD;

    float acc[4][4] = {};
    float ks_acc[4] = {};

    for (int tile = 0; tile < CHUNK1 / 64; ++tile) {
        const int s_base = s_chunk0 + tile * 64;
        __syncthreads();   // previous tile's compute reads done before overwrite
        // --- stage 64x64 K tile (feature-mapped) and V tile, float4 loads ---
        #pragma unroll
        for (int i = 0; i < 4; ++i) {
            const int idx = t + i * 256;     // float4 index 0..1023
            const int row = idx >> 4;        // 0..63
            const int c4  = idx & 15;        // 0..15
            const size_t goff = (size_t)(s_base + row) * DD + c4 * 4;
            float4 kk = *(const float4*)(kb + goff);
            kk.x = fmap(kk.x); kk.y = fmap(kk.y);
            kk.z = fmap(kk.z); kk.w = fmap(kk.w);
            *(float4*)(Ks + row * 64 + c4 * 4) = kk;
            float4 vv = *(const float4*)(vb + goff);
            *(float4*)(Vs + row * 64 + c4 * 4) = vv;
        }
        __syncthreads();
        // --- accumulate outer products over the 64 s values ---
        #pragma unroll 4
        for (int s = 0; s < 64; ++s) {
            float4 kf4 = *(const float4*)(Ks + s * 64 + d0);
            float4 vv4 = *(const float4*)(Vs + s * 64 + e0);
            const float kf[4] = {kf4.x, kf4.y, kf4.z, kf4.w};
            const float vvv[4] = {vv4.x, vv4.y, vv4.z, vv4.w};
            #pragma unroll
            for (int i = 0; i < 4; ++i) {
                #pragma unroll
                for (int j = 0; j < 4; ++j) acc[i][j] += kf[i] * vvv[j];
                ks_acc[i] += kf[i];
            }
        }
    }

    // --- commit partials ---
    float* kvb = kv_ws + (size_t)b * DD * DD;
    #pragma unroll
    for (int i = 0; i < 4; ++i) {
        #pragma unroll
        for (int j = 0; j < 4; ++j) {
            atomicAdd(kvb + (d0 + i) * DD + e0 + j, acc[i][j]);
        }
    }
    if (egrp == 0) {
        #pragma unroll
        for (int i = 0; i < 4; ++i) {
            atomicAdd(ksum_ws + b * DD + d0 + i, ks_acc[i]);
        }
    }
}

// -------------------------------------------------------------------------
// Phase 2: o[b][s][e] = (sum_d fmap(q[b][s][d]) * kv[b][d][e])
//                       / max(sum_d fmap(q[b][s][d]) * ksum[b][d], 1e-4)
// grid (C2, B), block 256.
// -------------------------------------------------------------------------
__global__ __launch_bounds__(256) void phase2_kernel(
    const float* __restrict__ q,
    const float* __restrict__ kv_ws,
    const float* __restrict__ ksum_ws,
    float* __restrict__ o)
{
    __shared__ float kvS[64 * 64];
    __shared__ float ksS[64];
    __shared__ float qS[64 * 68];   // padded stride 68 (16B-aligned rows)

    const int t = threadIdx.x;
    const int b = blockIdx.y;
    const int s_chunk0 = blockIdx.x * CHUNK2;
    const int sgrp = t >> 4;   // 0..15
    const int egrp = t & 15;   // 0..15
    const int s0 = sgrp * 4;
    const int e0 = egrp * 4;

    // --- load kv (4096 floats) + ksum (64) into LDS ---
    {
        const float4* kvb = (const float4*)(kv_ws + (size_t)b * DD * DD);
        #pragma unroll
        for (int i = 0; i < 4; ++i) {
            const int idx = t + i * 256;
            ((float4*)kvS)[idx] = kvb[idx];
        }
        if (t < 16) ((float4*)ksS)[t] = ((const float4*)(ksum_ws + b * DD))[t];
    }

    const float* qb = q + (size_t)b * SS * DD;
    float*       ob = o + (size_t)b * SS * DD;

    for (int tile = 0; tile < CHUNK2 / 64; ++tile) {
        const int s_base = s_chunk0 + tile * 64;
        __syncthreads();   // qS safe to overwrite (also orders kv load on iter 0)
        // --- stage feature-mapped Q tile ---
        #pragma unroll
        for (int i = 0; i < 4; ++i) {
            const int idx = t + i * 256;
            const int row = idx >> 4;
            const int c4  = idx & 15;
            float4 qq = *(const float4*)(qb + (size_t)(s_base + row) * DD + c4 * 4);
            qq.x = fmap(qq.x); qq.y = fmap(qq.y);
            qq.z = fmap(qq.z); qq.w = fmap(qq.w);
            *(float4*)(qS + row * 68 + c4 * 4) = qq;
        }
        __syncthreads();

        float acc[4][4] = {};
        float dacc[4] = {};
        #pragma unroll 4
        for (int dc = 0; dc < 16; ++dc) {       // 4-wide d chunks
            float4 kst = *(const float4*)(ksS + dc * 4);
            const float ks4[4] = {kst.x, kst.y, kst.z, kst.w};
            float qv[4][4];
            #pragma unroll
            for (int sr = 0; sr < 4; ++sr) {
                float4 x = *(const float4*)(qS + (s0 + sr) * 68 + dc * 4);
                qv[sr][0] = x.x; qv[sr][1] = x.y; qv[sr][2] = x.z; qv[sr][3] = x.w;
            }
            #pragma unroll
            for (int dj = 0; dj < 4; ++dj) {
                float4 kv4 = *(const float4*)(kvS + (dc * 4 + dj) * 64 + e0);
                const float kvr[4] = {kv4.x, kv4.y, kv4.z, kv4.w};
                #pragma unroll
                for (int sr = 0; sr < 4; ++sr) {
                    const float qq = qv[sr][dj];
                    acc[sr][0] += qq * kvr[0];
                    acc[sr][1] += qq * kvr[1];
                    acc[sr][2] += qq * kvr[2];
                    acc[sr][3] += qq * kvr[3];
                    dacc[sr]   += qq * ks4[dj];
                }
            }
        }
        // --- divide + store ---
        #pragma unroll
        for (int sr = 0; sr < 4; ++sr) {
            const float r = 1.0f / fmaxf(dacc[sr], 1e-4f);
            float4 outv;
            outv.x = acc[sr][0] * r;
            outv.y = acc[sr][1] * r;
            outv.z = acc[sr][2] * r;
            outv.w = acc[sr][3] * r;
            *(float4*)(ob + (size_t)(s_base + s0 + sr) * DD + e0) = outv;
        }
    }
}

extern "C" void kernel_launch(void* const* d_in, const int* in_sizes, int n_in,
                              void* d_out, int out_size, void* d_ws, size_t ws_size,
                              hipStream_t stream) {
    const float* q = (const float*)d_in[0];
    const float* k = (const float*)d_in[1];
    const float* v = (const float*)d_in[2];
    float* o = (float*)d_out;

    float* kv_ws   = (float*)d_ws;                       // B*D*D floats
    float* ksum_ws = kv_ws + (size_t)BB * DD * DD;       // B*D floats
    const size_t ws_bytes = ((size_t)BB * DD * DD + (size_t)BB * DD) * sizeof(float);

    // Workspace is re-poisoned to 0xAA before every timed launch -> zero it.
    hipMemsetAsync(d_ws, 0, ws_bytes, stream);

    dim3 g1(C1, BB), g2(C2, BB), blk(256);
    phase1_kernel<<<g1, blk, 0, stream>>>(k, v, kv_ws, ksum_ws);
    phase2_kernel<<<g2, blk, 0, stream>>>(q, kv_ws, ksum_ws, o);
}